// Round 1
// baseline (335.047 us; speedup 1.0000x reference)
//
#include <hip/hip_runtime.h>
#include <math.h>

// Problem constants (match reference.py)
#define HS_D       1024   // input_size
#define HS_MAXLEN  24     // max Huffman path depth

// One WAVE per example. The wave:
//   - loads its 16-float/lane fragment of x[n] ONCE (4 x float4, coalesced)
//     -> x traffic drops 7x vs the per-pair-wave version (221 MB -> 32 MB)
//   - loops over the example's path in step-PAIRS, each iteration loading
//     two W rows (8 x float4, coalesced) and doing two interleaved dots
//   - interleaved 64-lane butterfly reduce, masked softplus, accumulate
//   - lane 0 plain-stores the per-example sum into its OWN ws slot
//     -> no atomics, and no ws memset needed (finish reads only [0,n_ex))
// Invalid trailing step clamps its node to node0 (duplicate address -> L1
// hit, no extra HBM/L2 traffic). L is wave-uniform, so the pair loop has
// no divergence.
__global__ __launch_bounds__(256) void hsm_ex_kernel(
    const float* __restrict__ x,      // [N_EX, D]
    const float* __restrict__ W,      // [N_DEC, D]
    const int*   __restrict__ t,      // [N_EX]
    const int*   __restrict__ paths,  // [V, MAX_LEN]
    const float* __restrict__ codes,  // [V, MAX_LEN]
    const int*   __restrict__ lens,   // [V]
    float*       __restrict__ ws,     // [>= n_ex] floats (poison ok)
    int n_ex)
{
    const int tid  = threadIdx.x;
    const int lane = tid & 63;
    // Wave-uniform example index; readfirstlane pins it to an SGPR so the
    // t/lens/paths/codes accesses become scalar loads.
    const int n = __builtin_amdgcn_readfirstlane(blockIdx.x * 4 + (tid >> 6));
    if (n >= n_ex) return;

    const int leaf = __builtin_amdgcn_readfirstlane(t[n]);
    const int L    = __builtin_amdgcn_readfirstlane(lens[leaf]);

    // x fragment: 16 floats/lane, each float4 load is a contiguous 1 KB
    // wave-level segment.
    const float4* x4 = (const float4*)(x + (size_t)n * HS_D);
    float4 xf[4];
#pragma unroll
    for (int j = 0; j < 4; ++j) xf[j] = x4[j * 64 + lane];

    const int*   prow = paths + leaf * HS_MAXLEN;
    const float* crow = codes + leaf * HS_MAXLEN;

    float vsum = 0.0f;   // accumulated on ALL lanes (butterfly broadcasts)

    for (int l0 = 0; l0 < L; l0 += 2) {
        const int  l1 = l0 + 1;
        const bool v1 = (l1 < L);                   // wave-uniform

        const int   node0 = __builtin_amdgcn_readfirstlane(prow[l0]);
        const float c0    = crow[l0];
        const int   node1 = __builtin_amdgcn_readfirstlane(v1 ? prow[l1] : node0);
        const float c1    = v1 ? crow[l1] : 1.0f;

        const float4* w0 = (const float4*)(W + (size_t)node0 * HS_D);
        const float4* w1 = (const float4*)(W + (size_t)node1 * HS_D);

        // Issue all 8 W loads before consuming.
        float4 wf0[4], wf1[4];
#pragma unroll
        for (int j = 0; j < 4; ++j) wf0[j] = w0[j * 64 + lane];
#pragma unroll
        for (int j = 0; j < 4; ++j) wf1[j] = w1[j * 64 + lane];

        float d0 = 0.0f, d1 = 0.0f;
#pragma unroll
        for (int j = 0; j < 4; ++j) {
            d0 += xf[j].x * wf0[j].x + xf[j].y * wf0[j].y
                + xf[j].z * wf0[j].z + xf[j].w * wf0[j].w;
            d1 += xf[j].x * wf1[j].x + xf[j].y * wf1[j].y
                + xf[j].z * wf1[j].z + xf[j].w * wf1[j].w;
        }

        // Two interleaved 64-lane butterfly reductions (xor -> result on
        // all lanes, so softplus/accumulate below has no lane divergence).
#pragma unroll
        for (int off = 32; off > 0; off >>= 1) {
            d0 += __shfl_xor(d0, off);
            d1 += __shfl_xor(d1, off);
        }

        const float z0 = -c0 * d0;
        float v = fmaxf(z0, 0.0f) + log1pf(expf(-fabsf(z0)));
        if (v1) {                                   // wave-uniform branch
            const float z1 = -c1 * d1;
            v += fmaxf(z1, 0.0f) + log1pf(expf(-fabsf(z1)));
        }
        vsum += v;
    }

    if (lane == 0) ws[n] = vsum;   // plain store: slot owned by this wave
}

// One-block finish: sum ws[0..n_ex) -> out[0]. 256 threads, float4 loads,
// wave butterfly + tiny LDS cross-wave combine. No atomics, no zero-init.
__global__ __launch_bounds__(256) void hsm_finish_kernel(
    const float* __restrict__ ws, float* __restrict__ out, int n_ex)
{
    __shared__ float part[4];
    const int tid = threadIdx.x;

    float s = 0.0f;
    const int n4 = n_ex >> 2;                       // float4 count
    const float4* w4 = (const float4*)ws;
    for (int k = tid; k < n4; k += 256) {
        const float4 v = w4[k];
        s += v.x + v.y + v.z + v.w;
    }
    // scalar tail (n_ex % 4 elements)
    if (tid < (n_ex & 3)) s += ws[(n_ex & ~3) + tid];

#pragma unroll
    for (int off = 32; off > 0; off >>= 1)
        s += __shfl_xor(s, off);

    if ((tid & 63) == 0) part[tid >> 6] = s;
    __syncthreads();
    if (tid == 0) out[0] = part[0] + part[1] + part[2] + part[3];
}

extern "C" void kernel_launch(void* const* d_in, const int* in_sizes, int n_in,
                              void* d_out, int out_size, void* d_ws, size_t ws_size,
                              hipStream_t stream) {
    const float* x     = (const float*)d_in[0];
    const float* W     = (const float*)d_in[1];
    const int*   t     = (const int*)  d_in[2];
    const int*   paths = (const int*)  d_in[3];
    const float* codes = (const float*)d_in[4];
    const int*   lens  = (const int*)  d_in[5];
    float* out = (float*)d_out;
    float* ws  = (float*)d_ws;

    const int n_ex = in_sizes[2];  // t has N_EX elements

    // One wave per example; 4 waves per 256-thread block.
    const int n_blocks = (n_ex + 3) / 4;
    hsm_ex_kernel<<<n_blocks, 256, 0, stream>>>(x, W, t, paths, codes, lens,
                                                ws, n_ex);
    hsm_finish_kernel<<<1, 256, 0, stream>>>(ws, out, n_ex);
}

// Round 2
// 328.441 us; speedup vs baseline: 1.0201x; 1.0201x over previous
//
#include <hip/hip_runtime.h>
#include <math.h>

// Problem constants (match reference.py)
#define HS_D       1024   // input_size
#define HS_MAXLEN  24     // max Huffman path depth
#define HS_MAXPAIR 12     // max step-pairs per example
#define HS_NBUCKET 512    // partial-sum buckets

// ws layout (bytes):
//   [0, 4)         : int   pair-allocation cursor (atomic)
//   [64, 64+2048)  : float buckets[512]
//   [4096, ...)    : u64   worklist entries (one per valid step-pair)
#define WS_BUCKET_OFF 64
#define WS_WL_OFF     4096

// Worklist entry encoding:
//   lo32 = node0 | node1<<16                     (N_DEC = 50256 < 2^16)
//   hi32 = n(bits 0..23) | c0sign<<24 | c1sign<<25 | v1<<26 | valid<<28
// Bit 28 chosen as VALID because it is 0 in both zero-fill and the 0xAA
// poison pattern (0xAAAAAAAA has only odd bits set) -> tail waves reading
// unwritten entries always see invalid and exit.

// Build kernel: one thread per example. Walks the dependent chain
// t[n] -> lens -> paths/codes ONCE per example (instead of once per wave),
// packs each valid step-pair into an 8-byte entry, appends via an atomic
// cursor. 128 single-wave blocks; per-thread latency ~1.5k cycles -> ~3 us.
__global__ __launch_bounds__(64) void hsm_build_kernel(
    const int*   __restrict__ t,      // [N_EX]
    const int*   __restrict__ paths,  // [V, MAX_LEN]
    const float* __restrict__ codes,  // [V, MAX_LEN]
    const int*   __restrict__ lens,   // [V]
    int*                 counter,     // ws cursor (zeroed)
    unsigned long long* __restrict__ wl,  // worklist (zeroed)
    int n_ex)
{
    const int n = blockIdx.x * 64 + threadIdx.x;
    if (n >= n_ex) return;

    const int leaf  = t[n];
    const int L     = lens[leaf];
    const int npair = (L + 1) >> 1;

    // Load the full 24-entry paths/codes rows vectorized (rows are 96 B,
    // 16-B aligned). Unpack with static indices -> stays in registers.
    const int4*   p4 = (const int4*)(paths + leaf * HS_MAXLEN);
    const float4* c4 = (const float4*)(codes + leaf * HS_MAXLEN);
    int   pa[HS_MAXLEN];
    float ca[HS_MAXLEN];
#pragma unroll
    for (int j = 0; j < HS_MAXLEN / 4; ++j) {
        const int4   pv = p4[j];
        const float4 cv = c4[j];
        pa[4*j+0] = pv.x; pa[4*j+1] = pv.y; pa[4*j+2] = pv.z; pa[4*j+3] = pv.w;
        ca[4*j+0] = cv.x; ca[4*j+1] = cv.y; ca[4*j+2] = cv.z; ca[4*j+3] = cv.w;
    }

    const int base = atomicAdd(counter, npair);

#pragma unroll
    for (int p = 0; p < HS_MAXPAIR; ++p) {
        if (p < npair) {
            const int  l0 = 2 * p, l1 = l0 + 1;
            const bool v1 = (l1 < L);
            const int  node0 = pa[l0];
            const int  node1 = v1 ? pa[l1] : node0;  // clamp -> L1 dup hit
            const unsigned c0s = (ca[l0] < 0.0f) ? 1u : 0u;
            const unsigned c1s = (v1 && ca[l1] < 0.0f) ? 1u : 0u;
            const unsigned lo  = (unsigned)node0 | ((unsigned)node1 << 16);
            const unsigned hi  = (unsigned)n | (c0s << 24) | (c1s << 25)
                               | (v1 ? (1u << 26) : 0u) | (1u << 28);
            wl[base + p] = ((unsigned long long)hi << 32) | lo;
        }
    }
}

// One WAVE per worklist entry. One 8-byte uniform load replaces the old
// 3-deep t->lens->paths scalar chain; all 12 float4 loads issue right
// after it. Invalid/tail entries exit on that single load.
__global__ __launch_bounds__(256) void hsm_pair_kernel(
    const float* __restrict__ x,      // [N_EX, D]
    const float* __restrict__ W,      // [N_DEC, D]
    const unsigned long long* __restrict__ wl,
    float*       __restrict__ buckets)
{
    const int tid  = threadIdx.x;
    const int lane = tid & 63;
    const int gw   = blockIdx.x * 4 + (tid >> 6);

    const unsigned long long e = wl[gw];          // uniform addr -> broadcast
    const unsigned hi = (unsigned)(e >> 32);
    if (!(hi & (1u << 28))) return;               // wave-uniform exit

    const unsigned lo = (unsigned)e;
    const int n     = __builtin_amdgcn_readfirstlane((int)(hi & 0xFFFFFF));
    const int node0 = __builtin_amdgcn_readfirstlane((int)(lo & 0xFFFFu));
    const int node1 = __builtin_amdgcn_readfirstlane((int)(lo >> 16));
    const float c0  = (hi & (1u << 24)) ? -1.0f : 1.0f;
    const float c1  = (hi & (1u << 25)) ? -1.0f : 1.0f;
    const float v1f = (hi & (1u << 26)) ? 1.0f : 0.0f;

    const float4* x4 = (const float4*)(x + (size_t)n     * HS_D);
    const float4* w0 = (const float4*)(W + (size_t)node0 * HS_D);
    const float4* w1 = (const float4*)(W + (size_t)node1 * HS_D);

    // Issue all 12 loads before consuming (48 VGPRs of payload).
    float4 xf[4], wf0[4], wf1[4];
#pragma unroll
    for (int j = 0; j < 4; ++j) xf[j]  = x4[j * 64 + lane];
#pragma unroll
    for (int j = 0; j < 4; ++j) wf0[j] = w0[j * 64 + lane];
#pragma unroll
    for (int j = 0; j < 4; ++j) wf1[j] = w1[j * 64 + lane];

    float d0 = 0.0f, d1 = 0.0f;
#pragma unroll
    for (int j = 0; j < 4; ++j) {
        d0 += xf[j].x * wf0[j].x + xf[j].y * wf0[j].y
            + xf[j].z * wf0[j].z + xf[j].w * wf0[j].w;
        d1 += xf[j].x * wf1[j].x + xf[j].y * wf1[j].y
            + xf[j].z * wf1[j].z + xf[j].w * wf1[j].w;
    }

    // Two interleaved 64-lane butterfly reductions.
#pragma unroll
    for (int off = 32; off > 0; off >>= 1) {
        d0 += __shfl_xor(d0, off);
        d1 += __shfl_xor(d1, off);
    }

    const float z0 = -c0 * d0;
    float v = fmaxf(z0, 0.0f) + log1pf(expf(-fabsf(z0)));
    const float z1 = -c1 * d1;
    v += v1f * (fmaxf(z1, 0.0f) + log1pf(expf(-fabsf(z1))));

    if (lane == 0) atomicAdd(&buckets[gw & (HS_NBUCKET - 1)], v);
}

// One-block finish: sum the 512 buckets -> out[0].
__global__ __launch_bounds__(256) void hsm_finish_kernel(
    const float* __restrict__ buckets, float* __restrict__ out)
{
    __shared__ float part[4];
    const int tid = threadIdx.x;
    float s = buckets[tid] + buckets[tid + 256];
#pragma unroll
    for (int off = 32; off > 0; off >>= 1)
        s += __shfl_xor(s, off);
    if ((tid & 63) == 0) part[tid >> 6] = s;
    __syncthreads();
    if (tid == 0) out[0] = part[0] + part[1] + part[2] + part[3];
}

extern "C" void kernel_launch(void* const* d_in, const int* in_sizes, int n_in,
                              void* d_out, int out_size, void* d_ws, size_t ws_size,
                              hipStream_t stream) {
    const float* x     = (const float*)d_in[0];
    const float* W     = (const float*)d_in[1];
    const int*   t     = (const int*)  d_in[2];
    const int*   paths = (const int*)  d_in[3];
    const float* codes = (const float*)d_in[4];
    const int*   lens  = (const int*)  d_in[5];
    float* out = (float*)d_out;

    int*                counter = (int*)d_ws;
    float*              buckets = (float*)((char*)d_ws + WS_BUCKET_OFF);
    unsigned long long* wl      = (unsigned long long*)((char*)d_ws + WS_WL_OFF);

    const int n_ex      = in_sizes[2];        // t has N_EX elements
    const int max_pairs = n_ex * HS_MAXPAIR;

    // Zero cursor + buckets + worklist (+4 entries pad for the last
    // partial block's waves). ~790 KB -> ~1 us.
    hipMemsetAsync(d_ws, 0, WS_WL_OFF + (size_t)(max_pairs + 4) * 8, stream);

    hsm_build_kernel<<<(n_ex + 63) / 64, 64, 0, stream>>>(
        t, paths, codes, lens, counter, wl, n_ex);

    const int n_blocks = (max_pairs + 3) / 4;  // 4 waves per 256-thr block
    hsm_pair_kernel<<<n_blocks, 256, 0, stream>>>(x, W, wl, buckets);
    hsm_finish_kernel<<<1, 256, 0, stream>>>(buckets, out);
}